// Round 1
// baseline (199.775 us; speedup 1.0000x reference)
//
#include <hip/hip_runtime.h>
#include <stdint.h>

#define S_LEN 2048
#define NH 16
#define DH 64
#define DM 1024  // NH*DH

typedef __attribute__((ext_vector_type(8))) short short8;
typedef __attribute__((ext_vector_type(4))) float f32x4;

__device__ __forceinline__ unsigned short f2bf(float f) {
  union { float f; uint32_t u; } c; c.f = f;
  uint32_t u = c.u;
  return (unsigned short)((u + 0x7FFFu + ((u >> 16) & 1u)) >> 16);
}

// ---------- W (1024x1024 fp32, [d][e]) -> Wt bf16 [e][d] ----------
__global__ __launch_bounds__(256) void wtrans_kernel(const float* __restrict__ W,
                                                     unsigned short* __restrict__ Wt) {
  __shared__ __align__(16) unsigned short tile[64 * 72];
  const int tid = threadIdx.x;
  const int e0 = blockIdx.x << 6;
  const int d0 = blockIdx.y << 6;
#pragma unroll
  for (int i = 0; i < 4; ++i) {
    int idx = tid + i * 256;
    int d = idx >> 4;
    int ec = (idx & 15) << 2;
    float4 w = *(const float4*)(W + (size_t)(d0 + d) * DM + e0 + ec);
    tile[(ec + 0) * 72 + d] = f2bf(w.x);
    tile[(ec + 1) * 72 + d] = f2bf(w.y);
    tile[(ec + 2) * 72 + d] = f2bf(w.z);
    tile[(ec + 3) * 72 + d] = f2bf(w.w);
  }
  __syncthreads();
#pragma unroll
  for (int i = 0; i < 2; ++i) {
    int idx = tid + i * 256;
    int e = idx >> 3;
    int dc = (idx & 7) << 3;
    uint4 v = *(const uint4*)&tile[e * 72 + dc];
    *(uint4*)(Wt + (size_t)(e0 + e) * DM + d0 + dc) = v;
  }
}

// ---------- flash attention: one block = (b,h, 64-row q-tile) ----------
__global__ __launch_bounds__(256) void attn_kernel(const float* __restrict__ Q,
                                                   const float* __restrict__ K,
                                                   const float* __restrict__ V,
                                                   unsigned short* __restrict__ merged) {
  __shared__ __align__(16) unsigned short k_lds[64 * 72];  // [key][d]
  __shared__ __align__(16) unsigned short v_lds[64 * 72];  // [d][key]
  __shared__ __align__(16) unsigned short p_lds[4 * 16 * 72];

  const int tid = threadIdx.x;
  const int wave = tid >> 6;
  const int lane = tid & 63;
  const int t = lane & 15;
  const int qd = lane >> 4;

  const int bid = blockIdx.x;
  const int qt = 31 - (bid >> 5);  // heavy q-tiles dispatched first
  const int bh = bid & 31;
  const int h = bh & 15;
  const int b = bh >> 4;

  const int q0 = qt << 6;
  const int row0 = q0 + (wave << 4);
  const size_t base = (size_t)b * (S_LEN * DM) + (size_t)h * DH;  // + s*DM + d

  // Q fragments (A-layout: m=lane&15, k=quad*8+j), softmax scale folded in
  short8 qfrag[2];
  {
    const float* qp = Q + base + (size_t)(row0 + t) * DM + (qd << 3);
#pragma unroll
    for (int kk = 0; kk < 2; ++kk) {
      float4 f0 = *(const float4*)(qp + kk * 32);
      float4 f1 = *(const float4*)(qp + kk * 32 + 4);
      short8 fr;
      fr[0] = (short)f2bf(f0.x * 0.125f);
      fr[1] = (short)f2bf(f0.y * 0.125f);
      fr[2] = (short)f2bf(f0.z * 0.125f);
      fr[3] = (short)f2bf(f0.w * 0.125f);
      fr[4] = (short)f2bf(f1.x * 0.125f);
      fr[5] = (short)f2bf(f1.y * 0.125f);
      fr[6] = (short)f2bf(f1.z * 0.125f);
      fr[7] = (short)f2bf(f1.w * 0.125f);
      qfrag[kk] = fr;
    }
  }

  const f32x4 fzero = {0.f, 0.f, 0.f, 0.f};
  float m_r[4], l_r[4];
  f32x4 o_acc[4];
#pragma unroll
  for (int r = 0; r < 4; ++r) { m_r[r] = -INFINITY; l_r[r] = 0.f; }
#pragma unroll
  for (int nb = 0; nb < 4; ++nb) o_acc[nb] = fzero;

  const int ntiles = qt + 1;
  for (int tile = 0; tile < ntiles; ++tile) {
    const int kt0 = tile << 6;
    __syncthreads();
    // stage K (64 keys x 64 d, bf16)
#pragma unroll
    for (int i = 0; i < 4; ++i) {
      int idx = tid + i * 256;
      int key = idx >> 4;
      int dd = (idx & 15) << 2;
      float4 kv = *(const float4*)(K + base + (size_t)(kt0 + key) * DM + dd);
      uint2 u;
      u.x = (uint32_t)f2bf(kv.x) | ((uint32_t)f2bf(kv.y) << 16);
      u.y = (uint32_t)f2bf(kv.z) | ((uint32_t)f2bf(kv.w) << 16);
      *(uint2*)&k_lds[key * 72 + dd] = u;
    }
    // stage V transposed: v_lds[d][key]
#pragma unroll
    for (int i = 0; i < 4; ++i) {
      int idx = tid + i * 256;
      int dd = idx & 63;
      int key0 = (idx >> 6) << 2;
      const float* vp = V + base + (size_t)(kt0 + key0) * DM + dd;
      float v0 = vp[0], v1 = vp[DM], v2 = vp[2 * DM], v3 = vp[3 * DM];
      uint2 u;
      u.x = (uint32_t)f2bf(v0) | ((uint32_t)f2bf(v1) << 16);
      u.y = (uint32_t)f2bf(v2) | ((uint32_t)f2bf(v3) << 16);
      *(uint2*)&v_lds[dd * 72 + key0] = u;
    }
    __syncthreads();

    // S = Q*K^T (pre-scaled): 4 col-blocks of 16x16
    f32x4 sc[4];
#pragma unroll
    for (int cb = 0; cb < 4; ++cb) {
      short8 b0 = *(const short8*)&k_lds[(cb * 16 + t) * 72 + (qd << 3)];
      short8 b1 = *(const short8*)&k_lds[(cb * 16 + t) * 72 + 32 + (qd << 3)];
      f32x4 a = fzero;
      a = __builtin_amdgcn_mfma_f32_16x16x32_bf16(qfrag[0], b0, a, 0, 0, 0);
      a = __builtin_amdgcn_mfma_f32_16x16x32_bf16(qfrag[1], b1, a, 0, 0, 0);
      sc[cb] = a;
    }

    if (tile == qt) {  // causal mask, only the diagonal tile
#pragma unroll
      for (int cb = 0; cb < 4; ++cb)
#pragma unroll
        for (int r = 0; r < 4; ++r) {
          int keyg = kt0 + cb * 16 + t;
          int rowg = row0 + qd * 4 + r;
          if (keyg > rowg) sc[cb][r] = -INFINITY;
        }
    }

    // online softmax (rows live in lanes sharing quad; reduce across 16 lanes)
    float alpha[4];
#pragma unroll
    for (int r = 0; r < 4; ++r) {
      float mx = fmaxf(fmaxf(sc[0][r], sc[1][r]), fmaxf(sc[2][r], sc[3][r]));
      mx = fmaxf(mx, __shfl_xor(mx, 1, 16));
      mx = fmaxf(mx, __shfl_xor(mx, 2, 16));
      mx = fmaxf(mx, __shfl_xor(mx, 4, 16));
      mx = fmaxf(mx, __shfl_xor(mx, 8, 16));
      float mnew = fmaxf(m_r[r], mx);
      alpha[r] = __expf(m_r[r] - mnew);
      m_r[r] = mnew;
    }
#pragma unroll
    for (int cb = 0; cb < 4; ++cb)
#pragma unroll
      for (int r = 0; r < 4; ++r)
        sc[cb][r] = __expf(sc[cb][r] - m_r[r]);
#pragma unroll
    for (int r = 0; r < 4; ++r) {
      float s4 = sc[0][r] + sc[1][r] + sc[2][r] + sc[3][r];
      s4 += __shfl_xor(s4, 1, 16);
      s4 += __shfl_xor(s4, 2, 16);
      s4 += __shfl_xor(s4, 4, 16);
      s4 += __shfl_xor(s4, 8, 16);
      l_r[r] = l_r[r] * alpha[r] + s4;
    }
#pragma unroll
    for (int nb = 0; nb < 4; ++nb)
#pragma unroll
      for (int r = 0; r < 4; ++r)
        o_acc[nb][r] *= alpha[r];

    // P: C-layout -> LDS -> A-layout (per-wave scratch, no cross-wave barrier)
    const int pbase = wave * (16 * 72);
#pragma unroll
    for (int cb = 0; cb < 4; ++cb)
#pragma unroll
      for (int r = 0; r < 4; ++r)
        p_lds[pbase + (qd * 4 + r) * 72 + cb * 16 + t] = f2bf(sc[cb][r]);

    asm volatile("s_waitcnt lgkmcnt(0)" ::: "memory");

#pragma unroll
    for (int kk = 0; kk < 2; ++kk) {
      short8 pa = *(const short8*)&p_lds[pbase + t * 72 + kk * 32 + (qd << 3)];
#pragma unroll
      for (int nb = 0; nb < 4; ++nb) {
        short8 vb = *(const short8*)&v_lds[(nb * 16 + t) * 72 + kk * 32 + (qd << 3)];
        o_acc[nb] = __builtin_amdgcn_mfma_f32_16x16x32_bf16(pa, vb, o_acc[nb], 0, 0, 0);
      }
    }
  }

  // epilogue: merged[b, s, h*64 + d] = O / l
  float invl[4];
#pragma unroll
  for (int r = 0; r < 4; ++r) invl[r] = 1.f / l_r[r];
#pragma unroll
  for (int nb = 0; nb < 4; ++nb)
#pragma unroll
    for (int r = 0; r < 4; ++r) {
      int s = row0 + qd * 4 + r;
      merged[(size_t)(b * S_LEN + s) * DM + h * DH + nb * 16 + t] =
          f2bf(o_acc[nb][r] * invl[r]);
    }
}

// ---------- out = merged(4096x1024 bf16) @ W  via Wt[e][d], fp32 out ----------
__global__ __launch_bounds__(256) void gemm_kernel(const unsigned short* __restrict__ A,
                                                   const unsigned short* __restrict__ Bt,
                                                   float* __restrict__ C) {
  __shared__ __align__(16) unsigned short a_lds[64 * 72];
  __shared__ __align__(16) unsigned short b_lds[64 * 72];
  const int tid = threadIdx.x;
  const int wave = tid >> 6;
  const int lane = tid & 63;
  const int t = lane & 15;
  const int qd = lane >> 4;
  const int n0 = blockIdx.x << 6;
  const int m0 = blockIdx.y << 6;

  const f32x4 fzero = {0.f, 0.f, 0.f, 0.f};
  f32x4 acc[4];
#pragma unroll
  for (int nb = 0; nb < 4; ++nb) acc[nb] = fzero;

  for (int kt = 0; kt < DM; kt += 64) {
    __syncthreads();
#pragma unroll
    for (int i = 0; i < 2; ++i) {
      int idx = tid + i * 256;
      int row = idx >> 3;
      int dc = (idx & 7) << 3;
      *(uint4*)&a_lds[row * 72 + dc] = *(const uint4*)(A + (size_t)(m0 + row) * DM + kt + dc);
      *(uint4*)&b_lds[row * 72 + dc] = *(const uint4*)(Bt + (size_t)(n0 + row) * DM + kt + dc);
    }
    __syncthreads();
#pragma unroll
    for (int kk = 0; kk < 2; ++kk) {
      short8 af = *(const short8*)&a_lds[(wave * 16 + t) * 72 + kk * 32 + (qd << 3)];
#pragma unroll
      for (int nb = 0; nb < 4; ++nb) {
        short8 bf = *(const short8*)&b_lds[(nb * 16 + t) * 72 + kk * 32 + (qd << 3)];
        acc[nb] = __builtin_amdgcn_mfma_f32_16x16x32_bf16(af, bf, acc[nb], 0, 0, 0);
      }
    }
  }
#pragma unroll
  for (int nb = 0; nb < 4; ++nb)
#pragma unroll
    for (int r = 0; r < 4; ++r)
      C[(size_t)(m0 + wave * 16 + qd * 4 + r) * DM + n0 + nb * 16 + t] = acc[nb][r];
}

extern "C" void kernel_launch(void* const* d_in, const int* in_sizes, int n_in,
                              void* d_out, int out_size, void* d_ws, size_t ws_size,
                              hipStream_t stream) {
  // setup_inputs order: pre_q, pre_v, pre_k, output_weights, out_seq_len, d_model
  const float* pre_q = (const float*)d_in[0];
  const float* pre_v = (const float*)d_in[1];
  const float* pre_k = (const float*)d_in[2];
  const float* W     = (const float*)d_in[3];
  float* out = (float*)d_out;

  unsigned short* Wt = (unsigned short*)d_ws;                 // 1024*1024 bf16 = 2 MB
  unsigned short* merged = Wt + (size_t)DM * DM;              // 4096*1024 bf16 = 8 MB

  wtrans_kernel<<<dim3(16, 16), 256, 0, stream>>>(W, Wt);
  attn_kernel<<<dim3(1024), 256, 0, stream>>>(pre_q, pre_k, pre_v, merged);
  gemm_kernel<<<dim3(16, 64), 256, 0, stream>>>(merged, Wt, out);
}